// Round 3
// baseline (554.901 us; speedup 1.0000x reference)
//
#include <hip/hip_runtime.h>
#include <hip/hip_bf16.h>
#include <stdint.h>

#define M_DIM 8192
#define N_DIM 4096
#define K_DIM 4096

#define BM 256
#define BN 256
#define BK 64
#define NT (K_DIM / BK)   // 64 K-tiles
#define NHALF (NT * 2)    // 128 K-halves (32 cols each)

typedef __bf16 bf16x8 __attribute__((ext_vector_type(8)));
typedef float f32x4 __attribute__((ext_vector_type(4)));

// ---------------------------------------------------------------- helpers
__device__ __forceinline__ unsigned short f2bf(float f) {
  unsigned int u = __float_as_uint(f);
  u += 0x7fffu + ((u >> 16) & 1u);
  return (unsigned short)(u >> 16);
}
__device__ __forceinline__ unsigned int pack2(float lo, float hi) {
  return (unsigned int)f2bf(lo) | ((unsigned int)f2bf(hi) << 16);
}
__device__ __forceinline__ void async_copy16(const void* g, void* l) {
  __builtin_amdgcn_global_load_lds(
      (__attribute__((address_space(1))) void*)(g),
      (__attribute__((address_space(3))) void*)(l),
      16, 0, 0);
}

// ------------------------------------------------ prepass 1: A fp32->bf16
// 4 elems/thread: float4 load (16 B/lane), uint2 store (8 B/lane) — ideal
// coalescing (prev version used 64 B lane stride: issue-rate anti-pattern).
__global__ __launch_bounds__(256) void convert_a_kernel(
    const float* __restrict__ in, unsigned short* __restrict__ out) {
  size_t t = (size_t)blockIdx.x * 256 + threadIdx.x;
  size_t base = t * 4;
  float4 v = *(const float4*)(in + base);
  uint2 o;
  o.x = pack2(v.x, v.y);
  o.y = pack2(v.z, v.w);
  *(uint2*)(out + base) = o;
}

// --------------------------- prepass 2: Wt[o][i] = bf16(W[i][o]*Mask[i][o])
#define TS 72
__global__ __launch_bounds__(256) void maskT_kernel(
    const float* __restrict__ W, const float* __restrict__ Msk,
    unsigned short* __restrict__ Wt) {
  __shared__ unsigned short tile[64 * TS];
  const int t = threadIdx.x;
  const size_t i0 = (size_t)blockIdx.y * 64;
  const size_t o0 = (size_t)blockIdx.x * 64;

  const int o4 = (t & 15) * 4;
  const int i4 = (t >> 4) * 4;
  float4 w[4], m[4];
#pragma unroll
  for (int r = 0; r < 4; ++r) {
    const size_t gi = (i0 + i4 + r) * N_DIM + o0 + o4;
    w[r] = *(const float4*)(W + gi);
    m[r] = *(const float4*)(Msk + gi);
  }
  float e[4][4];
#pragma unroll
  for (int r = 0; r < 4; ++r) {
    e[r][0] = w[r].x * m[r].x; e[r][1] = w[r].y * m[r].y;
    e[r][2] = w[r].z * m[r].z; e[r][3] = w[r].w * m[r].w;
  }
#pragma unroll
  for (int c = 0; c < 4; ++c) {
    uint2 packed;
    packed.x = pack2(e[0][c], e[1][c]);
    packed.y = pack2(e[2][c], e[3][c]);
    *(uint2*)(tile + (o4 + c) * TS + i4) = packed;
  }
  __syncthreads();

  const int o_l = t >> 2;
  const int iseg = (t & 3) * 16;
  uint4 a = *(const uint4*)(tile + o_l * TS + iseg);
  uint4 b = *(const uint4*)(tile + o_l * TS + iseg + 8);
  unsigned short* dst = Wt + (o0 + o_l) * K_DIM + i0 + iseg;
  ((uint4*)dst)[0] = a;
  ((uint4*)dst)[1] = b;
}

// --------------------------------------- main GEMM: 256x256, 4-slot ring
// A: bf16 [M][K]; Bt: bf16 [N][K]; C: fp32 [M][N]
// 512 threads = 8 waves (2M x 4N), per-wave output 128x64.
// LDS 128 KiB = ring of 4 slots x 32 KB; slot s = K-half h&3, holding
// A[256][32] (8192 sh) + B[256][32] (8192 sh) for 32 K-columns.
// Tile t consumes halves 2t (phases 0,1) and 2t+1 (phases 2,3); each phase
// does 16 MFMA/wave (one M-half x all N x one K-half).
// Pipeline (the R2 fix): stage(2t+3)@ph0, stage(2t+4)@ph2 -> issue-to-gate
// distance 5 phases (~850 cyc) vs previous 3 (~500) which stalled on HBM.
// Gates: counted vmcnt(8) (=2 stages in flight) end of ph1 (covers half
// 2t+1) and end of ph3 (covers half 2t+2); vmcnt(0) in last 2 tiles (tail
// exactness: last stage h=127 issues t=62 ph0; vmcnt(8) can't guarantee it
// at t=63). Each wave gates its OWN loads; the following s_barrier joins ->
// all waves' loads for gated halves complete (issue order is uniform).
// Race-freedom: stage(2t+3) writes slot of half 2t-1, last ds_read drained
// by ph3(t-1) lgkmcnt(0) before its end barrier; issued after. Same for
// stage(2t+4) vs half 2t (drained ph1).
// Swizzle (rule #21, both-sides): physical seg p = quad ^ ((row>>1)&3)
// (4 segs/row); stage pre-swizzles the GLOBAL source col with the same
// involution, LDS stays linear for global_load_lds. 16B-group coverage per
// 64-lane ds_read_b128: 8 lanes per group, balanced -> 0 extra cycles.
__global__ __launch_bounds__(512, 2) void gemm_bf16_kernel(
    const unsigned short* __restrict__ A,
    const unsigned short* __restrict__ Bt,
    float* __restrict__ C) {
  __shared__ unsigned short lds[65536];  // 128 KiB = 4 x 16384 shorts

  const int tid  = threadIdx.x;
  const int wave = tid >> 6;
  const int lane = tid & 63;
  const int l16  = lane & 15;
  const int quad = lane >> 4;
  const int wm   = (wave >> 2) * 128;   // 2 M-waves
  const int wn   = (wave & 3) * 64;     // 4 N-waves

  // XCD-aware bijective swizzle: 512 blocks, 64/XCD = 2 bn-cols x 32 bm-rows
  const int flat = blockIdx.y * gridDim.x + blockIdx.x;
  const int xcd  = flat & 7;
  const int slot = flat >> 3;
  const int bx   = xcd * 2 + (slot & 1);
  const int by   = slot >> 1;
  const size_t bm = (size_t)by * BM;
  const size_t bn = (size_t)bx * BN;

  // ---- staging pointers: wave w covers rows 16w..16w+15 (+128 for load1)
  // lane l -> row sl = l>>2, phys seg ps = l&3; global seg = ps ^ ((row>>1)&3)
  // (row>>1)&3 == (l>>3)&3 since chunk bases are multiples of 8 rows.
  const int sl = lane >> 2;
  const int qs = (lane & 3) ^ ((lane >> 3) & 3);
  const unsigned short* pa0 = A  + (bm + wave * 16 + sl) * (size_t)K_DIM + qs * 8;
  const unsigned short* pa1 = pa0 + (size_t)128 * K_DIM;
  const unsigned short* pb0 = Bt + (bn + wave * 16 + sl) * (size_t)K_DIM + qs * 8;
  const unsigned short* pb1 = pb0 + (size_t)128 * K_DIM;

  auto stage = [&](int h) {
    const size_t off = (size_t)h * 32;  // half h = global cols [32h, 32h+32)
    unsigned short* d = lds + (h & 3) * 16384 + wave * 512;
    async_copy16(pa0 + off, d);
    async_copy16(pa1 + off, d + 4096);
    async_copy16(pb0 + off, d + 8192);
    async_copy16(pb1 + off, d + 12288);
  };

  // reader: lane (l16,quad) gets row-base+l16, phys seg quad^((l16>>1)&3)
  // -> logical K-seg = quad (stage/read involutions cancel)
  const int sxq = (quad ^ ((l16 >> 1) & 3)) * 8;  // element offset in row

  f32x4 acc[8][4] = {};
  bf16x8 afr[4], bfr[4], bfr2[4];

  // prologue: stage halves 0,1,2; gate half 0 (newer: 1,2 = 8 loads)
  stage(0); stage(1); stage(2);
  asm volatile("s_waitcnt vmcnt(8)" ::: "memory");
  __builtin_amdgcn_s_barrier();
  asm volatile("" ::: "memory");

  for (int t = 0; t < NT; ++t) {
    const unsigned short* S0 = lds + ((2 * t) & 3) * 16384;      // half 2t
    const unsigned short* S1 = lds + ((2 * t + 1) & 3) * 16384;  // half 2t+1
    const bool deep = (t < NT - 2);

    // ---- phase 0: Kh0, M-half0; stage(2t+3)
#pragma unroll
    for (int i = 0; i < 4; ++i)
      afr[i] = *(const bf16x8*)(S0 + (wm + i * 16 + l16) * 32 + sxq);
#pragma unroll
    for (int j = 0; j < 4; ++j)
      bfr[j] = *(const bf16x8*)(S0 + 8192 + (wn + j * 16 + l16) * 32 + sxq);
    if (2 * t + 3 < NHALF) stage(2 * t + 3);
    asm volatile("" ::: "memory");
    __builtin_amdgcn_s_barrier();
    asm volatile("s_waitcnt lgkmcnt(0)" ::: "memory");
    __builtin_amdgcn_sched_barrier(0);
    __builtin_amdgcn_s_setprio(1);
#pragma unroll
    for (int i = 0; i < 4; ++i)
#pragma unroll
      for (int j = 0; j < 4; ++j)
        acc[i][j] = __builtin_amdgcn_mfma_f32_16x16x32_bf16(
            afr[i], bfr[j], acc[i][j], 0, 0, 0);
    __builtin_amdgcn_sched_barrier(0);
    __builtin_amdgcn_s_setprio(0);
    asm volatile("" ::: "memory");
    __builtin_amdgcn_s_barrier();
    asm volatile("" ::: "memory");

    // ---- phase 1: Kh0, M-half1; gate half 2t+1
#pragma unroll
    for (int i = 0; i < 4; ++i)
      afr[i] = *(const bf16x8*)(S0 + (wm + 64 + i * 16 + l16) * 32 + sxq);
    asm volatile("" ::: "memory");
    __builtin_amdgcn_s_barrier();
    asm volatile("s_waitcnt lgkmcnt(0)" ::: "memory");
    __builtin_amdgcn_sched_barrier(0);
    __builtin_amdgcn_s_setprio(1);
#pragma unroll
    for (int i = 0; i < 4; ++i)
#pragma unroll
      for (int j = 0; j < 4; ++j)
        acc[4 + i][j] = __builtin_amdgcn_mfma_f32_16x16x32_bf16(
            afr[i], bfr[j], acc[4 + i][j], 0, 0, 0);
    __builtin_amdgcn_sched_barrier(0);
    __builtin_amdgcn_s_setprio(0);
    if (deep) {
      asm volatile("s_waitcnt vmcnt(8)" ::: "memory");
    } else {
      asm volatile("s_waitcnt vmcnt(0)" ::: "memory");
    }
    __builtin_amdgcn_s_barrier();
    asm volatile("" ::: "memory");

    // ---- phase 2: Kh1, M-half0; stage(2t+4)
#pragma unroll
    for (int i = 0; i < 4; ++i)
      afr[i] = *(const bf16x8*)(S1 + (wm + i * 16 + l16) * 32 + sxq);
#pragma unroll
    for (int j = 0; j < 4; ++j)
      bfr2[j] = *(const bf16x8*)(S1 + 8192 + (wn + j * 16 + l16) * 32 + sxq);
    if (2 * t + 4 < NHALF) stage(2 * t + 4);
    asm volatile("" ::: "memory");
    __builtin_amdgcn_s_barrier();
    asm volatile("s_waitcnt lgkmcnt(0)" ::: "memory");
    __builtin_amdgcn_sched_barrier(0);
    __builtin_amdgcn_s_setprio(1);
#pragma unroll
    for (int i = 0; i < 4; ++i)
#pragma unroll
      for (int j = 0; j < 4; ++j)
        acc[i][j] = __builtin_amdgcn_mfma_f32_16x16x32_bf16(
            afr[i], bfr2[j], acc[i][j], 0, 0, 0);
    __builtin_amdgcn_sched_barrier(0);
    __builtin_amdgcn_s_setprio(0);
    asm volatile("" ::: "memory");
    __builtin_amdgcn_s_barrier();
    asm volatile("" ::: "memory");

    // ---- phase 3: Kh1, M-half1; gate half 2t+2 (next tile)
#pragma unroll
    for (int i = 0; i < 4; ++i)
      afr[i] = *(const bf16x8*)(S1 + (wm + 64 + i * 16 + l16) * 32 + sxq);
    asm volatile("" ::: "memory");
    __builtin_amdgcn_s_barrier();
    asm volatile("s_waitcnt lgkmcnt(0)" ::: "memory");
    __builtin_amdgcn_sched_barrier(0);
    __builtin_amdgcn_s_setprio(1);
#pragma unroll
    for (int i = 0; i < 4; ++i)
#pragma unroll
      for (int j = 0; j < 4; ++j)
        acc[4 + i][j] = __builtin_amdgcn_mfma_f32_16x16x32_bf16(
            afr[i], bfr2[j], acc[4 + i][j], 0, 0, 0);
    __builtin_amdgcn_sched_barrier(0);
    __builtin_amdgcn_s_setprio(0);
    if (deep) {
      asm volatile("s_waitcnt vmcnt(8)" ::: "memory");
    } else {
      asm volatile("s_waitcnt vmcnt(0)" ::: "memory");
    }
    __builtin_amdgcn_s_barrier();
    asm volatile("" ::: "memory");
  }

  // epilogue: C/D layout col=lane&15, row=quad*4+i  [verified m89/m91]
#pragma unroll
  for (int mt = 0; mt < 8; ++mt) {
    const size_t row0 = bm + wm + mt * 16 + quad * 4;
#pragma unroll
    for (int nt = 0; nt < 4; ++nt) {
      const size_t col = bn + wn + nt * 16 + l16;
      float* cp = C + row0 * N_DIM + col;
#pragma unroll
      for (int i = 0; i < 4; ++i)
        cp[(size_t)i * N_DIM] = acc[mt][nt][i];
    }
  }
}

// ------------------------------------------ fallback: fp32 tiled (insurance)
__global__ void gemm_f32_fallback(const float* __restrict__ A,
                                  const float* __restrict__ W,
                                  const float* __restrict__ Msk,
                                  float* __restrict__ C) {
  __shared__ float As[32][33];
  __shared__ float Bs[32][33];
  const int tx = threadIdx.x;
  const int ty = threadIdx.y;
  const size_t row0 = (size_t)blockIdx.y * 32;
  const size_t col0 = (size_t)blockIdx.x * 32;
  float acc[4] = {0.f, 0.f, 0.f, 0.f};
  for (int k0 = 0; k0 < K_DIM; k0 += 32) {
#pragma unroll
    for (int rr = 0; rr < 4; ++rr) {
      int rw = ty + rr * 8;
      As[rw][tx] = A[(row0 + rw) * K_DIM + k0 + tx];
      size_t gi = (size_t)(k0 + rw) * N_DIM + col0 + tx;
      Bs[rw][tx] = W[gi] * Msk[gi];
    }
    __syncthreads();
#pragma unroll
    for (int kk = 0; kk < 32; ++kk) {
      float b = Bs[kk][tx];
#pragma unroll
      for (int rr = 0; rr < 4; ++rr) acc[rr] += As[ty + rr * 8][kk] * b;
    }
    __syncthreads();
  }
#pragma unroll
  for (int rr = 0; rr < 4; ++rr)
    C[(row0 + ty + rr * 8) * N_DIM + col0 + tx] = acc[rr];
}

// ---------------------------------------------------------------- launcher
extern "C" void kernel_launch(void* const* d_in, const int* in_sizes, int n_in,
                              void* d_out, int out_size, void* d_ws,
                              size_t ws_size, hipStream_t stream) {
  const float* A   = (const float*)d_in[0];
  const float* W   = (const float*)d_in[1];
  const float* Msk = (const float*)d_in[2];
  float* C = (float*)d_out;

  const size_t bytesA = (size_t)M_DIM * K_DIM * sizeof(unsigned short);
  const size_t bytesB = (size_t)K_DIM * N_DIM * sizeof(unsigned short);

  if (ws_size >= bytesA + bytesB) {
    unsigned short* Abf = (unsigned short*)d_ws;
    unsigned short* Wt  = (unsigned short*)((char*)d_ws + bytesA);
    convert_a_kernel<<<dim3(((size_t)M_DIM * K_DIM) / 4 / 256), dim3(256), 0,
                       stream>>>(A, Abf);
    maskT_kernel<<<dim3(N_DIM / 64, K_DIM / 64), dim3(256), 0, stream>>>(
        W, Msk, Wt);
    gemm_bf16_kernel<<<dim3(N_DIM / BN, M_DIM / BM), dim3(512), 0, stream>>>(
        Abf, Wt, C);
  } else {
    gemm_f32_fallback<<<dim3(N_DIM / 32, M_DIM / 32), dim3(32, 8), 0,
                        stream>>>(A, W, Msk, C);
  }
}

// Round 4
// 543.445 us; speedup vs baseline: 1.0211x; 1.0211x over previous
//
#include <hip/hip_runtime.h>
#include <hip/hip_bf16.h>
#include <stdint.h>

#define M_DIM 8192
#define N_DIM 4096
#define K_DIM 4096

#define BM 256
#define BN 256
#define BK 64
#define NT (K_DIM / BK)   // 64 K-tiles
#define NH (NT * 4)       // 256 half-tiles (A0,A1,B0,B1 per K-tile)

typedef __bf16 bf16x8 __attribute__((ext_vector_type(8)));
typedef float f32x16 __attribute__((ext_vector_type(16)));

// ---------------------------------------------------------------- helpers
__device__ __forceinline__ unsigned short f2bf(float f) {
  unsigned int u = __float_as_uint(f);
  u += 0x7fffu + ((u >> 16) & 1u);
  return (unsigned short)(u >> 16);
}
__device__ __forceinline__ unsigned int pack2(float lo, float hi) {
  return (unsigned int)f2bf(lo) | ((unsigned int)f2bf(hi) << 16);
}
__device__ __forceinline__ void async_copy16(const void* g, void* l) {
  __builtin_amdgcn_global_load_lds(
      (__attribute__((address_space(1))) void*)(g),
      (__attribute__((address_space(3))) void*)(l),
      16, 0, 0);
}

// ------------------------------------------------ prepass 1: A fp32->bf16
__global__ __launch_bounds__(256) void convert_a_kernel(
    const float* __restrict__ in, unsigned short* __restrict__ out) {
  size_t t = (size_t)blockIdx.x * 256 + threadIdx.x;
  size_t base = t * 4;
  float4 v = *(const float4*)(in + base);
  uint2 o;
  o.x = pack2(v.x, v.y);
  o.y = pack2(v.z, v.w);
  *(uint2*)(out + base) = o;
}

// --------------------------- prepass 2: Wt[o][i] = bf16(W[i][o]*Mask[i][o])
#define TS 72
__global__ __launch_bounds__(256) void maskT_kernel(
    const float* __restrict__ W, const float* __restrict__ Msk,
    unsigned short* __restrict__ Wt) {
  __shared__ unsigned short tile[64 * TS];
  const int t = threadIdx.x;
  const size_t i0 = (size_t)blockIdx.y * 64;
  const size_t o0 = (size_t)blockIdx.x * 64;

  const int o4 = (t & 15) * 4;
  const int i4 = (t >> 4) * 4;
  float4 w[4], m[4];
#pragma unroll
  for (int r = 0; r < 4; ++r) {
    const size_t gi = (i0 + i4 + r) * N_DIM + o0 + o4;
    w[r] = *(const float4*)(W + gi);
    m[r] = *(const float4*)(Msk + gi);
  }
  float e[4][4];
#pragma unroll
  for (int r = 0; r < 4; ++r) {
    e[r][0] = w[r].x * m[r].x; e[r][1] = w[r].y * m[r].y;
    e[r][2] = w[r].z * m[r].z; e[r][3] = w[r].w * m[r].w;
  }
#pragma unroll
  for (int c = 0; c < 4; ++c) {
    uint2 packed;
    packed.x = pack2(e[0][c], e[1][c]);
    packed.y = pack2(e[2][c], e[3][c]);
    *(uint2*)(tile + (o4 + c) * TS + i4) = packed;
  }
  __syncthreads();

  const int o_l = t >> 2;
  const int iseg = (t & 3) * 16;
  uint4 a = *(const uint4*)(tile + o_l * TS + iseg);
  uint4 b = *(const uint4*)(tile + o_l * TS + iseg + 8);
  unsigned short* dst = Wt + (o0 + o_l) * K_DIM + i0 + iseg;
  ((uint4*)dst)[0] = a;
  ((uint4*)dst)[1] = b;
}

// ------------------------------- main GEMM: 256x256, 2 phases, 32x32x16 MFMA
// A: bf16 [M][K]; Bt: bf16 [N][K]; C: fp32 [M][N]
// 512 threads = 8 waves (2M x 4N), per-wave output 128x64 = 4 rowtiles x 2
// coltiles of 32x32; acc = f32x16[4][2] (128 VGPR).
// LDS 128 KiB = 2 buf x {A0,A1,B0,B1} halftiles of 16 KB (128 rows x 64 K).
// Swizzle (rule #21): LDS linear for global_load_lds; stage pre-swizzles the
// GLOBAL source seg q -> phys p = q ^ (row&7); reader applies the same XOR.
// Bank balance: 64-lane ds_read_b128 lands 8 lanes per 16B position,
// uniform -> 0 conflicts (same balance as the verified 16x16 reader).
// Phase A: read A-half(mh=0) 8x b128 + ALL B 8x b128; stage A-halves of
//   tile t+1 (other buffer; its last reads drained by phB(t-1) lgkm0 before
//   phB(t-1) end barrier -> race-free); barrier; lgkm0; 16 MFMA; barrier.
// Phase B: read A-half(mh=1) 8x b128 (reuse B frags); stage B-halves of
//   tile t+2 into CURRENT buffer's B slots (B only read in phA; every
//   wave's lgkm0 precedes phA end barrier -> deterministic race-free);
//   barrier; lgkm0; 16 MFMA; gate vmcnt(4); barrier.
// vmcnt ledger (2 loads/halftile): prologue stages h0,h1,h2,h3,h6,h7,
// gate vmcnt(4) -> tile0 landed, h6,h7 in flight (steady state).
// At end-phB(t) gate vmcnt(4): newest 4 loads = phB(t)'s B'' stages ->
// A'(phA(t)) and B'(phB(t-1)) = tile t+1 complete. Issue->gate >= 1.5
// merged phases (~2000 cyc) >> HBM latency. Tail: t>=NT-2 -> vmcnt(0).
__global__ __launch_bounds__(512, 2) void gemm_bf16_kernel(
    const unsigned short* __restrict__ A,
    const unsigned short* __restrict__ Bt,
    float* __restrict__ C) {
  __shared__ unsigned short lds[65536];  // 128 KiB

  const int tid  = threadIdx.x;
  const int wave = tid >> 6;
  const int lane = tid & 63;
  const int l31  = lane & 31;
  const int kg   = lane >> 5;           // K-group within fragment
  const int wm   = (wave >> 2) * 128;   // 2 M-waves
  const int wn   = (wave & 3) * 64;     // 4 N-waves

  // XCD-aware bijective swizzle: 512 blocks, 64/XCD = 2 bn-cols x 32 bm-rows
  const int flat = blockIdx.y * gridDim.x + blockIdx.x;
  const int xcd  = flat & 7;
  const int slot = flat >> 3;
  const int bx   = xcd * 2 + (slot & 1);
  const int by   = slot >> 1;
  const size_t bm = (size_t)by * BM;
  const size_t bn = (size_t)bx * BN;

  // staging: thread covers rows lr0 and lr0+64 of a 128x64 halftile;
  // phys 16B seg p0 holds global seg q0 = p0 ^ (row&7)  ((lr0+64)&7 == lr0&7)
  const int lr0 = tid >> 3;            // 0..63
  const int p0  = tid & 7;
  const int q0  = p0 ^ (lr0 & 7);
  const unsigned short* pa = A  + (bm + lr0) * (size_t)K_DIM + q0 * 8;
  const unsigned short* pb = Bt + (bn + lr0) * (size_t)K_DIM + q0 * 8;

  auto stage = [&](int h) {
    const int u    = h >> 2;           // K-tile
    const int hk   = h & 1;            // row half
    const int isB  = (h >> 1) & 1;     // A or B
    const int bufh = u & 1;
    const unsigned short* s =
        (isB ? pb : pa) + (size_t)(hk * 128) * K_DIM + u * 64;
    unsigned short* d =
        lds + bufh * 32768 + isB * 16384 + hk * 8192 + wave * 512;
    async_copy16(s, d);
    async_copy16(s + (size_t)64 * K_DIM, d + 4096);
  };

  const int lx = lane & 7;  // reader XOR (row&7 == lane&7 for all frag rows)

  f32x16 acc[4][2] = {};    // [rowtile 0..3][coltile 0..1]
  bf16x8 afr[2][4], bfr[2][4];  // [tile][kstep]

  // prologue: tile0 (h0..h3) + B of tile1 (h6,h7); gate tile0
  stage(0); stage(1); stage(2); stage(3); stage(6); stage(7);
  asm volatile("s_waitcnt vmcnt(4)" ::: "memory");
  __builtin_amdgcn_s_barrier();
  asm volatile("" ::: "memory");

  for (int t = 0; t < NT; ++t) {
    const unsigned short* Ab = lds + (t & 1) * 32768;
    const unsigned short* Bb = Ab + 16384;
    const bool deep = (t < NT - 2);

    // ================ phase A: rowtiles 0,1 (rows wm..wm+63); all B
#pragma unroll
    for (int rt = 0; rt < 2; ++rt) {
      const int rowA = wm + rt * 32 + l31;
      const unsigned short* base = Ab + (rowA >> 7) * 8192 + (rowA & 127) * 64;
#pragma unroll
      for (int s = 0; s < 4; ++s)
        afr[rt][s] = *(const bf16x8*)(base + ((2 * s + kg) ^ lx) * 8);
    }
#pragma unroll
    for (int ct = 0; ct < 2; ++ct) {
      const int rowB = wn + ct * 32 + l31;
      const unsigned short* base = Bb + (rowB >> 7) * 8192 + (rowB & 127) * 64;
#pragma unroll
      for (int s = 0; s < 4; ++s)
        bfr[ct][s] = *(const bf16x8*)(base + ((2 * s + kg) ^ lx) * 8);
    }
    if (4 * t + 4 < NH) stage(4 * t + 4);   // A0 of tile t+1
    if (4 * t + 5 < NH) stage(4 * t + 5);   // A1 of tile t+1
    asm volatile("" ::: "memory");
    __builtin_amdgcn_s_barrier();
    asm volatile("s_waitcnt lgkmcnt(0)" ::: "memory");
    __builtin_amdgcn_sched_barrier(0);
    __builtin_amdgcn_s_setprio(1);
#pragma unroll
    for (int rt = 0; rt < 2; ++rt)
#pragma unroll
      for (int ct = 0; ct < 2; ++ct)
#pragma unroll
        for (int s = 0; s < 4; ++s)
          acc[rt][ct] = __builtin_amdgcn_mfma_f32_32x32x16_bf16(
              afr[rt][s], bfr[ct][s], acc[rt][ct], 0, 0, 0);
    __builtin_amdgcn_sched_barrier(0);
    __builtin_amdgcn_s_setprio(0);
    asm volatile("" ::: "memory");
    __builtin_amdgcn_s_barrier();
    asm volatile("" ::: "memory");

    // ================ phase B: rowtiles 2,3 (rows wm+64..wm+127); reuse B
#pragma unroll
    for (int rt = 0; rt < 2; ++rt) {
      const int rowA = wm + 64 + rt * 32 + l31;
      const unsigned short* base = Ab + (rowA >> 7) * 8192 + (rowA & 127) * 64;
#pragma unroll
      for (int s = 0; s < 4; ++s)
        afr[rt][s] = *(const bf16x8*)(base + ((2 * s + kg) ^ lx) * 8);
    }
    if (4 * t + 10 < NH) stage(4 * t + 10);  // B0 of tile t+2
    if (4 * t + 11 < NH) stage(4 * t + 11);  // B1 of tile t+2
    asm volatile("" ::: "memory");
    __builtin_amdgcn_s_barrier();
    asm volatile("s_waitcnt lgkmcnt(0)" ::: "memory");
    __builtin_amdgcn_sched_barrier(0);
    __builtin_amdgcn_s_setprio(1);
#pragma unroll
    for (int rt = 0; rt < 2; ++rt)
#pragma unroll
      for (int ct = 0; ct < 2; ++ct)
#pragma unroll
        for (int s = 0; s < 4; ++s)
          acc[2 + rt][ct] = __builtin_amdgcn_mfma_f32_32x32x16_bf16(
              afr[rt][s], bfr[ct][s], acc[2 + rt][ct], 0, 0, 0);
    __builtin_amdgcn_sched_barrier(0);
    __builtin_amdgcn_s_setprio(0);
    if (deep) {
      asm volatile("s_waitcnt vmcnt(4)" ::: "memory");  // tile t+1 landed
    } else {
      asm volatile("s_waitcnt vmcnt(0)" ::: "memory");  // tail drain
    }
    __builtin_amdgcn_s_barrier();
    asm volatile("" ::: "memory");
  }

  // epilogue: 32x32 C/D layout col=lane&31, row=(reg&3)+8*(reg>>2)+4*(lane>>5)
  // [verified m74/m101]
#pragma unroll
  for (int mt = 0; mt < 4; ++mt) {
    const size_t rowbase = bm + wm + mt * 32 + 4 * kg;
#pragma unroll
    for (int ct = 0; ct < 2; ++ct) {
      const size_t col = bn + wn + ct * 32 + l31;
#pragma unroll
      for (int g = 0; g < 4; ++g) {
        float* cp = C + (rowbase + 8 * g) * N_DIM + col;
#pragma unroll
        for (int j = 0; j < 4; ++j)
          cp[(size_t)j * N_DIM] = acc[mt][ct][4 * g + j];
      }
    }
  }
}

// ------------------------------------------ fallback: fp32 tiled (insurance)
__global__ void gemm_f32_fallback(const float* __restrict__ A,
                                  const float* __restrict__ W,
                                  const float* __restrict__ Msk,
                                  float* __restrict__ C) {
  __shared__ float As[32][33];
  __shared__ float Bs[32][33];
  const int tx = threadIdx.x;
  const int ty = threadIdx.y;
  const size_t row0 = (size_t)blockIdx.y * 32;
  const size_t col0 = (size_t)blockIdx.x * 32;
  float acc[4] = {0.f, 0.f, 0.f, 0.f};
  for (int k0 = 0; k0 < K_DIM; k0 += 32) {
#pragma unroll
    for (int rr = 0; rr < 4; ++rr) {
      int rw = ty + rr * 8;
      As[rw][tx] = A[(row0 + rw) * K_DIM + k0 + tx];
      size_t gi = (size_t)(k0 + rw) * N_DIM + col0 + tx;
      Bs[rw][tx] = W[gi] * Msk[gi];
    }
    __syncthreads();
#pragma unroll
    for (int kk = 0; kk < 32; ++kk) {
      float b = Bs[kk][tx];
#pragma unroll
      for (int rr = 0; rr < 4; ++rr) acc[rr] += As[ty + rr * 8][kk] * b;
    }
    __syncthreads();
  }
#pragma unroll
  for (int rr = 0; rr < 4; ++rr)
    C[(row0 + ty + rr * 8) * N_DIM + col0 + tx] = acc[rr];
}

// ---------------------------------------------------------------- launcher
extern "C" void kernel_launch(void* const* d_in, const int* in_sizes, int n_in,
                              void* d_out, int out_size, void* d_ws,
                              size_t ws_size, hipStream_t stream) {
  const float* A   = (const float*)d_in[0];
  const float* W   = (const float*)d_in[1];
  const float* Msk = (const float*)d_in[2];
  float* C = (float*)d_out;

  const size_t bytesA = (size_t)M_DIM * K_DIM * sizeof(unsigned short);
  const size_t bytesB = (size_t)K_DIM * N_DIM * sizeof(unsigned short);

  if (ws_size >= bytesA + bytesB) {
    unsigned short* Abf = (unsigned short*)d_ws;
    unsigned short* Wt  = (unsigned short*)((char*)d_ws + bytesA);
    convert_a_kernel<<<dim3(((size_t)M_DIM * K_DIM) / 4 / 256), dim3(256), 0,
                       stream>>>(A, Abf);
    maskT_kernel<<<dim3(N_DIM / 64, K_DIM / 64), dim3(256), 0, stream>>>(
        W, Msk, Wt);
    gemm_bf16_kernel<<<dim3(N_DIM / BN, M_DIM / BM), dim3(512), 0, stream>>>(
        Abf, Wt, C);
  } else {
    gemm_f32_fallback<<<dim3(N_DIM / 32, M_DIM / 32), dim3(32, 8), 0,
                        stream>>>(A, W, Msk, C);
  }
}

// Round 5
// 519.497 us; speedup vs baseline: 1.0682x; 1.0461x over previous
//
#include <hip/hip_runtime.h>
#include <hip/hip_bf16.h>
#include <stdint.h>

#define M_DIM 8192
#define N_DIM 4096
#define K_DIM 4096

#define BM 256
#define BN 256
#define BK 64
#define NT (K_DIM / BK)   // 64 K-tiles
#define NH (NT * 4)       // 256 half-tiles (A0,A1,B0,B1 per K-tile)

typedef __bf16 bf16x8 __attribute__((ext_vector_type(8)));
typedef float f32x4 __attribute__((ext_vector_type(4)));

// ---------------------------------------------------------------- helpers
__device__ __forceinline__ unsigned short f2bf(float f) {
  unsigned int u = __float_as_uint(f);
  u += 0x7fffu + ((u >> 16) & 1u);
  return (unsigned short)(u >> 16);
}
__device__ __forceinline__ unsigned int pack2(float lo, float hi) {
  return (unsigned int)f2bf(lo) | ((unsigned int)f2bf(hi) << 16);
}
__device__ __forceinline__ void async_copy16(const void* g, void* l) {
  __builtin_amdgcn_global_load_lds(
      (__attribute__((address_space(1))) void*)(g),
      (__attribute__((address_space(3))) void*)(l),
      16, 0, 0);
}

// ------------------------------------------------ prepass 1: A fp32->bf16
__global__ __launch_bounds__(256) void convert_a_kernel(
    const float* __restrict__ in, unsigned short* __restrict__ out) {
  size_t t = (size_t)blockIdx.x * 256 + threadIdx.x;
  size_t base = t * 4;
  float4 v = *(const float4*)(in + base);
  uint2 o;
  o.x = pack2(v.x, v.y);
  o.y = pack2(v.z, v.w);
  *(uint2*)(out + base) = o;
}

// --------------------------- prepass 2: Wt[o][i] = bf16(W[i][o]*Mask[i][o])
#define TS 72
__global__ __launch_bounds__(256) void maskT_kernel(
    const float* __restrict__ W, const float* __restrict__ Msk,
    unsigned short* __restrict__ Wt) {
  __shared__ unsigned short tile[64 * TS];
  const int t = threadIdx.x;
  const size_t i0 = (size_t)blockIdx.y * 64;
  const size_t o0 = (size_t)blockIdx.x * 64;

  const int o4 = (t & 15) * 4;
  const int i4 = (t >> 4) * 4;
  float4 w[4], m[4];
#pragma unroll
  for (int r = 0; r < 4; ++r) {
    const size_t gi = (i0 + i4 + r) * N_DIM + o0 + o4;
    w[r] = *(const float4*)(W + gi);
    m[r] = *(const float4*)(Msk + gi);
  }
  float e[4][4];
#pragma unroll
  for (int r = 0; r < 4; ++r) {
    e[r][0] = w[r].x * m[r].x; e[r][1] = w[r].y * m[r].y;
    e[r][2] = w[r].z * m[r].z; e[r][3] = w[r].w * m[r].w;
  }
#pragma unroll
  for (int c = 0; c < 4; ++c) {
    uint2 packed;
    packed.x = pack2(e[0][c], e[1][c]);
    packed.y = pack2(e[2][c], e[3][c]);
    *(uint2*)(tile + (o4 + c) * TS + i4) = packed;
  }
  __syncthreads();

  const int o_l = t >> 2;
  const int iseg = (t & 3) * 16;
  uint4 a = *(const uint4*)(tile + o_l * TS + iseg);
  uint4 b = *(const uint4*)(tile + o_l * TS + iseg + 8);
  unsigned short* dst = Wt + (o0 + o_l) * K_DIM + i0 + iseg;
  ((uint4*)dst)[0] = a;
  ((uint4*)dst)[1] = b;
}

// -------------------- main GEMM: 256x256, 2 merged phases, 16x16x32 MFMA
// EXACT R2 addressing (measured 0 bank conflicts, MfmaUtil 50.2) with the
// only change being phase count 4 -> 2 (barriers/tile 8 -> 4, lgkm-drain
// windows 4 -> 2, MFMA clusters of 32).
// A: bf16 [M][K]; Bt: bf16 [N][K]; C: fp32 [M][N]
// 512 threads = 8 waves (2M x 4N), per-wave output 128x64.
// LDS 128 KiB: [2 buf][A 256x64 | B 256x64] bf16, double-buffered per K-tile.
// Swizzle (rule #21): LDS linear; global SOURCE seg q = p ^ (row&7);
// ds_read applies same XOR (R2-verified conflict-free).
// Phase A: read A-half0 (8 b128) + ALL B (8 b128); stage A0,A1 of tile t+1
//   (other buffer; its last reads drained by phB(t-1) lgkm0 before that
//   phase's end barrier -> race-free); barrier; lgkm0; 32 MFMA; barrier.
// Phase B: read A-half1 (8 b128, reuse B frags); stage B0,B1 of tile t+2
//   into CURRENT buffer's B slots (B only read in phA; every wave's lgkm0
//   precedes phA end barrier -> race-free); barrier; lgkm0; 32 MFMA;
//   gate vmcnt(4); barrier.
// vmcnt ledger (2 loads/halftile): prologue stages h0..h3,h6,h7 (12 loads),
// gate vmcnt(4) -> tile0 landed, h6,h7 in flight. Steady state: end-phB(t)
// gate vmcnt(4) leaves exactly phB(t)'s 4 B-loads in flight -> A(phA(t)) +
// B(phB(t-1)) = tile t+1 complete. Tail: t >= NT-2 -> vmcnt(0); stage
// guards cut h >= NH (last stages: A of t63 @phA(62) h252-253, B of t63
// @phB(61) h254-255).
__global__ __launch_bounds__(512, 2) void gemm_bf16_kernel(
    const unsigned short* __restrict__ A,
    const unsigned short* __restrict__ Bt,
    float* __restrict__ C) {
  __shared__ unsigned short lds[65536];  // 128 KiB

  const int tid  = threadIdx.x;
  const int wave = tid >> 6;
  const int lane = tid & 63;
  const int l16  = lane & 15;
  const int quad = lane >> 4;
  const int wm   = (wave >> 2) * 128;   // 2 M-waves
  const int wn   = (wave & 3) * 64;     // 4 N-waves

  // XCD-aware bijective swizzle: 512 blocks, 64/XCD = 2 bn-cols x 32 bm-rows
  const int flat = blockIdx.y * gridDim.x + blockIdx.x;
  const int xcd  = flat & 7;
  const int slot = flat >> 3;
  const int bx   = xcd * 2 + (slot & 1);
  const int by   = slot >> 1;
  const size_t bm = (size_t)by * BM;
  const size_t bn = (size_t)bx * BN;

  // staging: thread covers rows lr0 and lr0+64 of a 128x64 halftile;
  // phys 16B seg p0 holds global seg q0 = p0 ^ (row&7)  ((lr0+64)&7 == lr0&7)
  const int lr0 = tid >> 3;            // 0..63
  const int p0  = tid & 7;
  const int q0  = p0 ^ (lr0 & 7);
  const unsigned short* pa = A  + (bm + lr0) * (size_t)K_DIM + q0 * 8;
  const unsigned short* pb = Bt + (bn + lr0) * (size_t)K_DIM + q0 * 8;

  auto stage = [&](int h) {
    const int u    = h >> 2;           // K-tile
    const int hk   = h & 1;            // row half
    const int isB  = (h >> 1) & 1;     // A or B
    const int bufh = u & 1;
    const unsigned short* s =
        (isB ? pb : pa) + (size_t)(hk * 128) * K_DIM + u * 64;
    unsigned short* d =
        lds + bufh * 32768 + isB * 16384 + hk * 8192 + wave * 512;
    async_copy16(s, d);
    async_copy16(s + (size_t)64 * K_DIM, d + 4096);
  };

  const int sx = (l16 & 7) * 8;  // reader seg-XOR, in elements (R2-exact)

  f32x4 acc[8][4] = {};
  bf16x8 afr[4][2], bfr[4][2];

  // prologue: tile0 (h0..h3) + B of tile1 (h6,h7); gate tile0
  stage(0); stage(1); stage(2); stage(3); stage(6); stage(7);
  asm volatile("s_waitcnt vmcnt(4)" ::: "memory");
  __builtin_amdgcn_s_barrier();
  asm volatile("" ::: "memory");

  for (int t = 0; t < NT; ++t) {
    const unsigned short* Ab = lds + (t & 1) * 32768;
    const unsigned short* Bb = Ab + 16384;
    const bool deep = (t < NT - 2);
    const int h0 = 4 * t;

    // ========== phase A: M-half0 (mt 0..3) x all N; stage A0,A1 of t+1
#pragma unroll
    for (int i = 0; i < 4; ++i)
#pragma unroll
      for (int ks = 0; ks < 2; ++ks)
        afr[i][ks] = *(const bf16x8*)(Ab + (wm + i * 16 + l16) * 64 +
                                      ((ks * 32 + quad * 8) ^ sx));
#pragma unroll
    for (int j = 0; j < 4; ++j)
#pragma unroll
      for (int ks = 0; ks < 2; ++ks)
        bfr[j][ks] = *(const bf16x8*)(Bb + (wn + j * 16 + l16) * 64 +
                                      ((ks * 32 + quad * 8) ^ sx));
    if (h0 + 4 < NH) stage(h0 + 4);   // A0 of tile t+1
    if (h0 + 5 < NH) stage(h0 + 5);   // A1 of tile t+1
    asm volatile("" ::: "memory");
    __builtin_amdgcn_s_barrier();
    asm volatile("s_waitcnt lgkmcnt(0)" ::: "memory");
    __builtin_amdgcn_sched_barrier(0);
    __builtin_amdgcn_s_setprio(1);
#pragma unroll
    for (int i = 0; i < 4; ++i)
#pragma unroll
      for (int j = 0; j < 4; ++j)
#pragma unroll
        for (int ks = 0; ks < 2; ++ks)
          acc[i][j] = __builtin_amdgcn_mfma_f32_16x16x32_bf16(
              afr[i][ks], bfr[j][ks], acc[i][j], 0, 0, 0);
    __builtin_amdgcn_sched_barrier(0);
    __builtin_amdgcn_s_setprio(0);
    asm volatile("" ::: "memory");
    __builtin_amdgcn_s_barrier();
    asm volatile("" ::: "memory");

    // ========== phase B: M-half1 (mt 4..7), reuse B; stage B0,B1 of t+2
#pragma unroll
    for (int i = 0; i < 4; ++i)
#pragma unroll
      for (int ks = 0; ks < 2; ++ks)
        afr[i][ks] = *(const bf16x8*)(Ab + (wm + 64 + i * 16 + l16) * 64 +
                                      ((ks * 32 + quad * 8) ^ sx));
    if (h0 + 10 < NH) stage(h0 + 10);  // B0 of tile t+2
    if (h0 + 11 < NH) stage(h0 + 11);  // B1 of tile t+2
    asm volatile("" ::: "memory");
    __builtin_amdgcn_s_barrier();
    asm volatile("s_waitcnt lgkmcnt(0)" ::: "memory");
    __builtin_amdgcn_sched_barrier(0);
    __builtin_amdgcn_s_setprio(1);
#pragma unroll
    for (int i = 0; i < 4; ++i)
#pragma unroll
      for (int j = 0; j < 4; ++j)
#pragma unroll
        for (int ks = 0; ks < 2; ++ks)
          acc[4 + i][j] = __builtin_amdgcn_mfma_f32_16x16x32_bf16(
              afr[i][ks], bfr[j][ks], acc[4 + i][j], 0, 0, 0);
    __builtin_amdgcn_sched_barrier(0);
    __builtin_amdgcn_s_setprio(0);
    if (deep) {
      asm volatile("s_waitcnt vmcnt(4)" ::: "memory");  // tile t+1 landed
    } else {
      asm volatile("s_waitcnt vmcnt(0)" ::: "memory");  // tail drain
    }
    __builtin_amdgcn_s_barrier();
    asm volatile("" ::: "memory");
  }

  // epilogue: C/D layout col=lane&15, row=quad*4+i  [verified m89/m91]
#pragma unroll
  for (int mt = 0; mt < 8; ++mt) {
    const size_t row0 = bm + wm + mt * 16 + quad * 4;
#pragma unroll
    for (int nt = 0; nt < 4; ++nt) {
      const size_t col = bn + wn + nt * 16 + l16;
      float* cp = C + row0 * N_DIM + col;
#pragma unroll
      for (int i = 0; i < 4; ++i)
        cp[(size_t)i * N_DIM] = acc[mt][nt][i];
    }
  }
}

// ------------------------------------------ fallback: fp32 tiled (insurance)
__global__ void gemm_f32_fallback(const float* __restrict__ A,
                                  const float* __restrict__ W,
                                  const float* __restrict__ Msk,
                                  float* __restrict__ C) {
  __shared__ float As[32][33];
  __shared__ float Bs[32][33];
  const int tx = threadIdx.x;
  const int ty = threadIdx.y;
  const size_t row0 = (size_t)blockIdx.y * 32;
  const size_t col0 = (size_t)blockIdx.x * 32;
  float acc[4] = {0.f, 0.f, 0.f, 0.f};
  for (int k0 = 0; k0 < K_DIM; k0 += 32) {
#pragma unroll
    for (int rr = 0; rr < 4; ++rr) {
      int rw = ty + rr * 8;
      As[rw][tx] = A[(row0 + rw) * K_DIM + k0 + tx];
      size_t gi = (size_t)(k0 + rw) * N_DIM + col0 + tx;
      Bs[rw][tx] = W[gi] * Msk[gi];
    }
    __syncthreads();
#pragma unroll
    for (int kk = 0; kk < 32; ++kk) {
      float b = Bs[kk][tx];
#pragma unroll
      for (int rr = 0; rr < 4; ++rr) acc[rr] += As[ty + rr * 8][kk] * b;
    }
    __syncthreads();
  }
#pragma unroll
  for (int rr = 0; rr < 4; ++rr)
    C[(row0 + ty + rr * 8) * N_DIM + col0 + tx] = acc[rr];
}

// ---------------------------------------------------------------- launcher
extern "C" void kernel_launch(void* const* d_in, const int* in_sizes, int n_in,
                              void* d_out, int out_size, void* d_ws,
                              size_t ws_size, hipStream_t stream) {
  const float* A   = (const float*)d_in[0];
  const float* W   = (const float*)d_in[1];
  const float* Msk = (const float*)d_in[2];
  float* C = (float*)d_out;

  const size_t bytesA = (size_t)M_DIM * K_DIM * sizeof(unsigned short);
  const size_t bytesB = (size_t)K_DIM * N_DIM * sizeof(unsigned short);

  if (ws_size >= bytesA + bytesB) {
    unsigned short* Abf = (unsigned short*)d_ws;
    unsigned short* Wt  = (unsigned short*)((char*)d_ws + bytesA);
    convert_a_kernel<<<dim3(((size_t)M_DIM * K_DIM) / 4 / 256), dim3(256), 0,
                       stream>>>(A, Abf);
    maskT_kernel<<<dim3(N_DIM / 64, K_DIM / 64), dim3(256), 0, stream>>>(
        W, Msk, Wt);
    gemm_bf16_kernel<<<dim3(N_DIM / BN, M_DIM / BM), dim3(512), 0, stream>>>(
        Abf, Wt, C);
  } else {
    gemm_f32_fallback<<<dim3(N_DIM / 32, M_DIM / 32), dim3(32, 8), 0,
                        stream>>>(A, W, Msk, C);
  }
}